// Round 12
// baseline (147.040 us; speedup 1.0000x reference)
//
#include <hip/hip_runtime.h>

// Per-sample depthwise 7x7 cross-correlation, NHWC, SAME padding.
// inputs:  [B,H,W,C] fp32, kernels: [B,7,7,C] fp32, out: [B,H,W,C] fp32.
// out[b,y,x,c] = sum_{i,j} in[b, y+i-3, x+j-3, c] * ker[b,i,j,c]  (zero pad)
//
// R12 = R8 (fp16 dot2, weights packed in LDS, 64-VGPR tier) + DEPTH-2 tap
// prefetch: loads for input row r+2 are issued at the start of the pass that
// computes row r, and packed ~1.5 passes later -> ~700-800 cyc issue->use
// distance covers HBM latency (R8's depth-1 gave only ~400). Implemented as
// alternating A/B pass bodies over two staging register sets (+10 VGPRs vs
// R8's 40 -> ~50, inside the 64 tier). No occupancy attributes, no >2 unroll
// (R2/R6/R9 lessons: the allocator spills or balloons past 64 and loses 2x).

#define BB 32
#define HH 128
#define WW 128
#define CC 128
#define KH 7
#define KW 7

#define XPT 4                        // x outputs per thread
#define NTAP (XPT + KW - 1)          // 10 tap columns per thread
#define XG 8                         // x-groups per block (1024 threads / 128 c)
#define SLABW (XG * XPT)             // 32 output columns per block
#define NXS (WW / SLABW)             // 4 x-slabs
#define YSPLIT 4
#define YROWS (HH / YSPLIT)          // 32 output rows per block
#define GRID (BB * NXS * YSPLIT)     // 512 blocks = 2 per CU
#define WSLOTS 28                    // per-c packed-weight uints (7 rows x 4 pairs)
#define NPASS (YROWS + KH - 1)       // 38 single-row passes = 19 A/B pairs

typedef _Float16 half2_t __attribute__((ext_vector_type(2)));

static __device__ __forceinline__ half2_t pk(float a, float b) {
#if __has_builtin(__builtin_amdgcn_cvt_pkrtz)
    return __builtin_bit_cast(half2_t, __builtin_amdgcn_cvt_pkrtz(a, b));
#else
    half2_t r; r.x = (_Float16)a; r.y = (_Float16)b; return r;
#endif
}

static __device__ __forceinline__ float dot2f(unsigned w, half2_t t, float c) {
#if __has_builtin(__builtin_amdgcn_fdot2)
    return __builtin_amdgcn_fdot2(__builtin_bit_cast(half2_t, w), t, c, false);
#else
    half2_t wv = __builtin_bit_cast(half2_t, w);
    return fmaf((float)wv.x, (float)t.x, fmaf((float)wv.y, (float)t.y, c));
#endif
}

__global__ __launch_bounds__(1024) void crossconv_kernel(
    const float* __restrict__ in,
    const float* __restrict__ ker,
    float* __restrict__ out)
{
    __shared__ unsigned lds_w[CC * WSLOTS];   // 14336 B

    const int tid = threadIdx.x;
    const int c  = tid & (CC - 1);   // lanes contiguous in c -> coalesced
    const int xg = __builtin_amdgcn_readfirstlane(tid >> 7);   // 0..7, wave-uniform

    // Bijective XCD swizzle (GRID=512, 64 blocks/XCD = 4 whole samples).
    const int bid = blockIdx.x;
    const int swz = (bid & 7) * (GRID / 8) + (bid >> 3);
    const int b  = swz >> 4;         // 16 blocks per sample
    const int xs = (swz >> 2) & 3;
    const int yh = swz & 3;
    const int x0 = xs * SLABW + xg * XPT;  // wave-uniform (scalar)
    const int y0 = yh * YROWS;

    // Stage packed weights into LDS: slot s (0..27) -> row i=s>>2, pair q=s&3.
    // q<3: (w[i][2q], w[i][2q+1]); q==3: (w[i][6], 0).
    {
        const float* kb = ker + ((size_t)b * KH * KW) * CC + c;
        for (int s = xg; s < WSLOTS; s += XG) {
            const int i = s >> 2, q = s & 3;
            half2_t pr;
            if (q < 3) {
                const int f0 = i * KW + 2 * q;
                pr = pk(kb[f0 * CC], kb[(f0 + 1) * CC]);
            } else {
                pr = pk(kb[(i * KW + 6) * CC], 0.0f);
            }
            lds_w[c * WSLOTS + s] = __builtin_bit_cast(unsigned, pr);
        }
    }
    __syncthreads();

    const float* ib = in  + ((size_t)b * HH * WW) * CC;
    float*       ob = out + ((size_t)b * HH * WW) * CC;
    const unsigned* wlds = &lds_w[c * WSLOTS];

    const bool interior = (x0 >= 3) && (x0 + XPT + 2 < WW);

    // Issue (async) the 10 tap loads for row yi into t. Consumption (pack)
    // happens ~1.5 passes later; vmcnt wait lands there.
    auto issue_taps = [&](float* t, int yi) {
        if (yi < 0 || yi >= HH) {
            #pragma unroll
            for (int j = 0; j < NTAP; ++j) t[j] = 0.0f;
            return;
        }
        const float* row = ib + (size_t)yi * WW * CC + c;  // per-lane part: c only
        if (interior) {
            #pragma unroll
            for (int j = 0; j < NTAP; ++j)
                t[j] = row[(x0 - 3 + j) * CC];             // scalar offsets
        } else {
            #pragma unroll
            for (int j = 0; j < NTAP; ++j) {
                const int xx = x0 - 3 + j;
                t[j] = (xx >= 0 && xx < WW) ? row[xx * CC] : 0.0f;
            }
        }
    };

    // Sliding ring: acc[s][xo] partial for output row y = yi-3+s.
    float acc[KH][XPT];
    #pragma unroll
    for (int s = 0; s < KH; ++s)
        #pragma unroll
        for (int xo = 0; xo < XPT; ++xo) acc[s][xo] = 0.0f;

    const int yi0 = y0 - 3;

    // Packed taps for the CURRENT pass row:
    // e[k]=(t[2k],t[2k+1]) k=0..4 ; o[k]=(t[2k+1],t[2k+2]) k=0..3, o[4]=(t9,0).
    half2_t e[5], o[5];
    float tA[NTAP], tB[NTAP];

    // Prologue: row yi0 -> pack immediately (one exposed wait); issue row yi0+1.
    issue_taps(tA, yi0);
    #pragma unroll
    for (int k = 0; k < 5; ++k) e[k] = pk(tA[2 * k], tA[2 * k + 1]);
    #pragma unroll
    for (int k = 0; k < 4; ++k) o[k] = pk(tA[2 * k + 1], tA[2 * k + 2]);
    o[4] = pk(tA[9], 0.0f);
    issue_taps(tB, yi0 + 1);

    // One full pass: dots on current e/o for input row yi, store completed
    // output row, ring shift, then pack the NEXT row from tsrc.
    auto pass = [&](int yi, const float* tsrc) {
        // Keep per-pass LDS weight reads in the loop (hoisting 28 pairs would
        // blow the 64-VGPR tier and spill).
        asm volatile("" ::: "memory");

        #pragma unroll
        for (int i = 0; i < KH; ++i) {
            const uint4 wq = *(const uint4*)(wlds + i * 4);   // kernel row i
            const int s = 6 - i;
            #pragma unroll
            for (int xo = 0; xo < XPT; ++xo) {
                float a = acc[s][xo];
                if ((xo & 1) == 0) {
                    const int k0 = xo >> 1;
                    a = dot2f(wq.x, e[k0],     a);
                    a = dot2f(wq.y, e[k0 + 1], a);
                    a = dot2f(wq.z, e[k0 + 2], a);
                    a = dot2f(wq.w, e[k0 + 3], a);
                } else {
                    const int k0 = (xo - 1) >> 1;
                    a = dot2f(wq.x, o[k0],     a);
                    a = dot2f(wq.y, o[k0 + 1], a);
                    a = dot2f(wq.z, o[k0 + 2], a);
                    a = dot2f(wq.w, o[k0 + 3], a);
                }
                acc[s][xo] = a;
            }
        }

        const int y = yi - 3;
        if (y >= y0) {                       // upper bound guaranteed by loop end
            float* orow = ob + ((size_t)y * WW + x0) * CC + c;
            #pragma unroll
            for (int xo = 0; xo < XPT; ++xo)
                orow[xo * CC] = acc[0][xo];
        }

        // Shift ring, open fresh top slot.
        #pragma unroll
        for (int s = 0; s < KH - 1; ++s)
            #pragma unroll
            for (int xo = 0; xo < XPT; ++xo) acc[s][xo] = acc[s + 1][xo];
        #pragma unroll
        for (int xo = 0; xo < XPT; ++xo) acc[KH - 1][xo] = 0.0f;

        // Pack next row's taps (vmcnt wait lands here, ~1.5 passes after issue).
        #pragma unroll
        for (int k = 0; k < 5; ++k) e[k] = pk(tsrc[2 * k], tsrc[2 * k + 1]);
        #pragma unroll
        for (int k = 0; k < 4; ++k) o[k] = pk(tsrc[2 * k + 1], tsrc[2 * k + 2]);
        o[4] = pk(tsrc[9], 0.0f);
    };

    #pragma unroll 1
    for (int p = 0; p < NPASS / 2; ++p) {
        const int r = yi0 + 2 * p;
        // Body A: compute row r; issue row r+2 into tA; pack row r+1 from tB.
        issue_taps(tA, r + 2);
        pass(r, tB);
        // Body B: compute row r+1; issue row r+3 into tB; pack row r+2 from tA.
        issue_taps(tB, r + 3);
        pass(r + 1, tA);
    }
}

extern "C" void kernel_launch(void* const* d_in, const int* in_sizes, int n_in,
                              void* d_out, int out_size, void* d_ws, size_t ws_size,
                              hipStream_t stream) {
    const float* in  = (const float*)d_in[0];
    const float* ker = (const float*)d_in[1];
    float*       out = (float*)d_out;

    crossconv_kernel<<<GRID, 1024, 0, stream>>>(in, ker, out);
}